// Round 17
// baseline (158.380 us; speedup 1.0000x reference)
//
#include <hip/hip_runtime.h>
#include <hip/hip_bf16.h>
#include <stdint.h>

// Problem constants (from reference)
#define M_TOTAL 131072
#define K_DIM   512
#define N_RANK  256
#define NSEG    1024
#define KC      64              // k-chunk staged in LDS (64 bf16 per row)
#define NKC     (K_DIM / KC)    // 8
#define BM      128             // rows per block
#define NBLK    (M_TOTAL / BM)  // 1024 fused blocks
#define NB64    (M_TOTAL / 64)  // 2048 virtual 64-row groups (pass2 granularity)

typedef __attribute__((ext_vector_type(8))) short bf16x8;
typedef __attribute__((ext_vector_type(4))) float f32x4;

// Raw barrier: lgkmcnt(0) makes my ds_writes visible, vmcnt NOT drained.
#define BAR() do { \
    asm volatile("s_waitcnt lgkmcnt(0)" ::: "memory"); \
    __builtin_amdgcn_s_barrier(); \
} while (0)

__device__ inline short f2b(float f) {
    __hip_bfloat16 h = __float2bfloat16(f);
    return __builtin_bit_cast(short, h);
}

// fast tanh: t = sign(z) * (1 - 2/(e^{2|z|}+1))
__device__ inline float fast_tanh(float z) {
    float e = __expf(2.0f * fabsf(z));
    return copysignf(1.0f - 2.0f / (e + 1.0f), z);
}

// Kernel 1: init out to 1.0 (segment_prod identity for empty segments)
//           + convert W to bf16 in ws
__global__ void prep_kernel(const float* __restrict__ W,
                            __hip_bfloat16* __restrict__ Wb,
                            float* __restrict__ out) {
    int i = blockIdx.x * 256 + threadIdx.x;
    out[i] = 1.0f;
    if (i < N_RANK * K_DIM) Wb[i] = __float2bfloat16(W[i]);
}

// Kernel 2 (pass 1): fused GEMM + bias + tanh + in-register segmented product.
//
// R17: 2x4 wave grid (wr,wc) -- per-wave A-read halves to 8 ds_read_b128
// (R12's col-slice had every wave read the whole chunk: 8x LDS amplification,
// ~34% of the CU chunk slot). The R13/R14 spill is avoided by loading B ONE
// K-slice at a time (bfr[4]=16 regs, reused): regs = acc64+bfr16+sg16+addr
// ~= 116 <= 128-cap of (512,4) -> 2 blocks/CU.
// Schedule per chunk (mid-drain proven free in R16):
//   BAR; B(s0) loads [oldest -> counted wait]; G(kc+1) loads [fly over s0];
//   compute s0; vmcnt(0); STAGE_WRITE; B(s1) loads [ds_write covers L2 lat];
//   compute s1.
__launch_bounds__(512, 4)   // reg cap 128; spill canary = WRITE_SIZE balloon
__global__ void fused_kernel(const float* __restrict__ x,
                             const __hip_bfloat16* __restrict__ Wb,
                             const float* __restrict__ bias,
                             const int* __restrict__ seg,
                             float* __restrict__ out,
                             float* __restrict__ partial) {
    const int tid  = threadIdx.x;
    const int wave = tid >> 6;
    const int wr   = wave >> 2;       // 0..1 row-half
    const int wc   = wave & 3;        // 0..3 col-quarter
    const int lane = tid & 63;
    const int l16  = lane & 15;
    const int g    = lane >> 4;       // 0..3 (k-group / row-group)
    const int bid  = blockIdx.x;
    const int m0   = bid * BM;
    const int n0   = wc * 64;

    // LDS: A double-buffer, 2 x (128 rows x 128B bf16) = 32 KB.
    __shared__ alignas(16) char smem[32768];

    // ---- staging geometry: thread covers one 16B f32 slot, 4 slabs ----
    const int srow = tid >> 4;        // 0..31
    const int sc16 = tid & 15;

    f32x4 acc[4][4] = {};             // [m-frag][n-frag]
    f32x4 sg[4];                      // staged f32 for next chunk
    bf16x8 bfr[4];                    // B frags for ONE K-slice (reused s0,s1)

    #define STAGE_LOAD(kc_)                                                   \
        do {                                                                  \
            _Pragma("unroll")                                                 \
            for (int it = 0; it < 4; ++it)                                    \
                sg[it] = *reinterpret_cast<const f32x4*>(                     \
                    x + (size_t)(m0 + it * 32 + srow) * K_DIM + (kc_) * KC + sc16 * 4); \
        } while (0)

    #define STAGE_WRITE(buf_)                                                 \
        do {                                                                  \
            _Pragma("unroll")                                                 \
            for (int it = 0; it < 4; ++it) {                                  \
                const int row = it * 32 + srow;                               \
                short4 p;                                                     \
                p.x = f2b(sg[it][0]); p.y = f2b(sg[it][1]);                   \
                p.z = f2b(sg[it][2]); p.w = f2b(sg[it][3]);                   \
                *reinterpret_cast<short4*>(smem + (buf_) * 16384 + row * 128  \
                    + ((sc16 * 8) ^ ((row & 7) << 4))) = p;                   \
            }                                                                 \
        } while (0)

    #define B_LOAD(s_)                                                        \
        do {                                                                  \
            _Pragma("unroll")                                                 \
            for (int j = 0; j < 4; ++j)                                       \
                bfr[j] = *reinterpret_cast<const bf16x8*>(                    \
                    Wb + (size_t)(n0 + j * 16 + l16) * K_DIM + kc * KC        \
                       + (s_) * 32 + g * 8);                                  \
        } while (0)

    #define COMPUTE_SLICE(s_)                                                 \
        do {                                                                  \
            _Pragma("unroll")                                                 \
            for (int i = 0; i < 4; ++i) {                                     \
                const int row = wr * 64 + i * 16 + l16;                       \
                bf16x8 av = *reinterpret_cast<const bf16x8*>(                 \
                    smem + bufb + row * 128 +                                 \
                    (((s_) * 64 + g * 16) ^ ((row & 7) << 4)));               \
                _Pragma("unroll")                                             \
                for (int j = 0; j < 4; ++j)                                   \
                    acc[i][j] = __builtin_amdgcn_mfma_f32_16x16x32_bf16(      \
                        av, bfr[j], acc[i][j], 0, 0, 0);                      \
            }                                                                 \
        } while (0)

    // ---- prologue: stage chunk 0 into buf 0 ----
    STAGE_LOAD(0);
    asm volatile("s_waitcnt vmcnt(0)" ::: "memory");
    STAGE_WRITE(0);

    // ---- K loop: 8 chunks of 64, ONE barrier per chunk ----
    #pragma unroll
    for (int kc = 0; kc < NKC; ++kc) {
        BAR();   // buf[kc&1] visible to all; buf[(kc+1)&1] free to write

        // 1) B slice s=0 (oldest in queue -> counted B-use wait)
        B_LOAD(0);
        __builtin_amdgcn_sched_barrier(0);   // pin: B(s0) above G-loads

        // 2) G loads for chunk kc+1 (newest; fly across s0 compute)
        if (kc + 1 < NKC) STAGE_LOAD(kc + 1);
        __builtin_amdgcn_sched_barrier(0);   // pin: G above compute

        const int bufb = (kc & 1) * 16384;

        // 3a) compute K-slice 0 (4 ds_read_b128 + 16 MFMA)
        COMPUTE_SLICE(0);

        // 3b) drain G (free -- arrived during s0) + stage-write next chunk
        if (kc + 1 < NKC) {
            asm volatile("s_waitcnt vmcnt(0)" ::: "memory");
            STAGE_WRITE((kc + 1) & 1);
        }

        // 3c) B slice s=1 into the SAME bfr regs (L2 latency partially
        //     hidden behind the ds_write tail), then compute slice 1
        B_LOAD(1);
        COMPUTE_SLICE(1);
    }
    #undef STAGE_LOAD
    #undef STAGE_WRITE
    #undef B_LOAD
    #undef COMPUTE_SLICE

    // ---- bias + tanh in regs ----
    // D layout: col = lane&15, row(within 16x16) = (lane>>4)*4 + r
    #pragma unroll
    for (int j = 0; j < 4; ++j) {
        const float bj = bias[n0 + j * 16 + l16];
        #pragma unroll
        for (int i = 0; i < 4; ++i)
            #pragma unroll
            for (int r = 0; r < 4; ++r)
                acc[i][j][r] = fast_tanh(acc[i][j][r] + bj);
    }

    // ---- in-register segmented product over the wave's 64-row half ----
    // Wave (wr,wc): rows [m0+wr*64,+64), cols [wc*64,+64). vb = bid*2+wr.
    const int vb     = bid * 2 + wr;
    const int myseg  = seg[m0 + wr * 64 + lane];
    const int prevsg = (lane == 0) ? (myseg ^ 1) : seg[m0 + wr * 64 + lane - 1];
    uint64_t m = __ballot(myseg != prevsg);                  // run-start bits

    while (m) {
        const int start = (int)__builtin_ctzll(m);
        m &= m - 1;
        const int end = m ? (int)__builtin_ctzll(m) : 64;
        const int s   = __shfl(myseg, start);                // run's segment id

        float p[4] = {1.0f, 1.0f, 1.0f, 1.0f};
        #pragma unroll
        for (int i = 0; i < 4; ++i)
            #pragma unroll
            for (int r = 0; r < 4; ++r) {
                const int row = i * 16 + g * 4 + r;          // row within half
                const bool in = (row >= start) && (row < end);
                #pragma unroll
                for (int j = 0; j < 4; ++j)
                    p[j] *= in ? acc[i][j][r] : 1.0f;
            }
        #pragma unroll
        for (int j = 0; j < 4; ++j) {
            p[j] *= __shfl_xor(p[j], 16);
            p[j] *= __shfl_xor(p[j], 32);
        }
        if (g == 0) {
            #pragma unroll
            for (int j = 0; j < 4; ++j) {
                const int col = n0 + j * 16 + l16;
                if (start == 0)
                    partial[(size_t)(vb * 2 + 0) * N_RANK + col] = p[j];
                else if (end == 64)
                    partial[(size_t)(vb * 2 + 1) * N_RANK + col] = p[j];
                else
                    out[(size_t)s * N_RANK + col] = p[j];    // interior: exclusive
            }
        }
    }
}

// Kernel 3 (pass 2): combine boundary partials over 64-row groups (b = vb).
// Group b owns boundary segment s iff s first appears in group b. Interior
// segments were stored by pass 1; empty segments stay 1.0.
__global__ void pass2_kernel(const int* __restrict__ seg,
                             const float* __restrict__ partial,
                             float* __restrict__ out) {
    const int b   = blockIdx.x;
    const int col = threadIdx.x;      // 0..255
    const int sF    = seg[b * 64];
    const int sL    = seg[b * 64 + 63];
    const int prevL = (b == 0) ? -1 : seg[b * 64 - 1];

    if (prevL < sF) {                 // b owns its first segment
        float p = partial[(size_t)(b * 2 + 0) * N_RANK + col];
        for (int b2 = b + 1; b2 < NB64 && seg[b2 * 64] == sF; ++b2)
            p *= partial[(size_t)(b2 * 2 + 0) * N_RANK + col];
        out[(size_t)sF * N_RANK + col] = p;
    }
    if (sL != sF) {                   // b always owns sL when sL != sF
        float p = partial[(size_t)(b * 2 + 1) * N_RANK + col];
        for (int b2 = b + 1; b2 < NB64 && seg[b2 * 64] == sL; ++b2)
            p *= partial[(size_t)(b2 * 2 + 0) * N_RANK + col];
        out[(size_t)sL * N_RANK + col] = p;
    }
}

extern "C" void kernel_launch(void* const* d_in, const int* in_sizes, int n_in,
                              void* d_out, int out_size, void* d_ws, size_t ws_size,
                              hipStream_t stream) {
    const float* x   = (const float*)d_in[0];
    const float* W   = (const float*)d_in[1];
    const float* b   = (const float*)d_in[2];
    const int*   seg = (const int*)d_in[3];
    float*       out = (float*)d_out;
    __hip_bfloat16* Wb = (__hip_bfloat16*)d_ws;                       // 256 KB
    float* partial = (float*)((char*)d_ws + (1 << 20));               // 4 MB @ +1MB

    prep_kernel<<<(NSEG * N_RANK) / 256, 256, 0, stream>>>(W, Wb, out);
    fused_kernel<<<NBLK, 512, 0, stream>>>(x, Wb, b, seg, out, partial);
    pass2_kernel<<<NB64, 256, 0, stream>>>(seg, partial, out);
}

// Round 18
// 97.637 us; speedup vs baseline: 1.6221x; 1.6221x over previous
//
#include <hip/hip_runtime.h>
#include <hip/hip_bf16.h>
#include <stdint.h>

// Problem constants (from reference)
#define M_TOTAL 131072
#define K_DIM   512
#define N_RANK  256
#define NSEG    1024
#define KC      128             // k-chunk staged in LDS (128 bf16 per row)
#define NKC     (K_DIM / KC)    // 4 -- barrier count halved vs R12
#define BM      128             // rows per block
#define NBLK    (M_TOTAL / BM)  // 1024 fused blocks
#define NB64    (M_TOTAL / 64)  // 2048 virtual 64-row groups (pass2 granularity)

typedef __attribute__((ext_vector_type(8))) short bf16x8;
typedef __attribute__((ext_vector_type(4))) float f32x4;

// Raw barrier: lgkmcnt(0) makes my ds_writes visible, vmcnt NOT drained.
#define BAR() do { \
    asm volatile("s_waitcnt lgkmcnt(0)" ::: "memory"); \
    __builtin_amdgcn_s_barrier(); \
} while (0)

__device__ inline short f2b(float f) {
    __hip_bfloat16 h = __float2bfloat16(f);
    return __builtin_bit_cast(short, h);
}

// fast tanh: t = sign(z) * (1 - 2/(e^{2|z|}+1))
__device__ inline float fast_tanh(float z) {
    float e = __expf(2.0f * fabsf(z));
    return copysignf(1.0f - 2.0f / (e + 1.0f), z);
}

// Kernel 1: init out to 1.0 (segment_prod identity for empty segments)
//           + convert W to bf16 in ws
__global__ void prep_kernel(const float* __restrict__ W,
                            __hip_bfloat16* __restrict__ Wb,
                            float* __restrict__ out) {
    int i = blockIdx.x * 256 + threadIdx.x;
    out[i] = 1.0f;
    if (i < N_RANK * K_DIM) Wb[i] = __float2bfloat16(W[i]);
}

// Kernel 2 (pass 1): fused GEMM + bias + tanh + in-register segmented product.
//
// R18 = R12/R16 wave geometry (8-wave col-slice, the only shape that fits the
// 128-reg cap -- R13/R14/R17 all spilled deviating from it) with KC=128:
// 4 chunks instead of 8 -> per-chunk fixed cost (barrier rendezvous, waits,
// issue overhead) halves. R15 measured the inverse (2x chunks = +20 us).
//
// Register shape kept BYTE-IDENTICAL to R12: acc[8][2] + bfr[2][2] + sg[4].
// The chunk is processed in two sequential phases that REUSE bfr/sg:
//   BAR; B(s0,s1) [oldest]; G col-half0 [fly over s0/s1 compute];
//   compute s0,s1; vmcnt(0) [G0 landed -- free, proven R16]; write half0;
//   B(s2,s3); G col-half1; compute s2,s3; vmcnt(0); write half1.
// The mid vmcnt(0) asm("memory") also fences phase-B loads from hoisting
// into phase-A live ranges (spill protection).
__launch_bounds__(512, 4)   // reg cap 128; spill canary = WRITE_SIZE balloon
__global__ void fused_kernel(const float* __restrict__ x,
                             const __hip_bfloat16* __restrict__ Wb,
                             const float* __restrict__ bias,
                             const int* __restrict__ seg,
                             float* __restrict__ out,
                             float* __restrict__ partial) {
    const int tid  = threadIdx.x;
    const int wave = tid >> 6;        // 0..7 = column-slice
    const int lane = tid & 63;
    const int l16  = lane & 15;
    const int g    = lane >> 4;       // 0..3 (k-group / row-group)
    const int bid  = blockIdx.x;
    const int m0   = bid * BM;
    const int n0   = wave * 32;

    // LDS: A double-buffer, 2 x (128 rows x 256B bf16) = 64 KB.
    __shared__ alignas(16) char smem[65536];

    // ---- staging geometry: thread covers one 16B f32 slot, 4 slabs,
    //      per col-half h (KC=128 f32 = two 64-f32 halves) ----
    const int srow = tid >> 4;        // 0..31
    const int sc16 = tid & 15;

    f32x4 acc[8][2] = {};             // [m-frag][n-frag]
    f32x4 sg[4];                      // staged f32, reused per col-half
    bf16x8 bfr[2][2];                 // B frags for TWO K-slices (reused)

    #define STAGE_LOAD(kc_, h_)                                               \
        do {                                                                  \
            _Pragma("unroll")                                                 \
            for (int it = 0; it < 4; ++it)                                    \
                sg[it] = *reinterpret_cast<const f32x4*>(                     \
                    x + (size_t)(m0 + it * 32 + srow) * K_DIM + (kc_) * KC    \
                      + (h_) * 64 + sc16 * 4);                                \
        } while (0)

    #define STAGE_WRITE(buf_, h_)                                             \
        do {                                                                  \
            _Pragma("unroll")                                                 \
            for (int it = 0; it < 4; ++it) {                                  \
                const int row = it * 32 + srow;                               \
                short4 p;                                                     \
                p.x = f2b(sg[it][0]); p.y = f2b(sg[it][1]);                   \
                p.z = f2b(sg[it][2]); p.w = f2b(sg[it][3]);                   \
                *reinterpret_cast<short4*>(smem + (buf_) * 32768 + row * 256  \
                    + (((h_) * 128 + sc16 * 8) ^ ((row & 7) << 4))) = p;      \
            }                                                                 \
        } while (0)

    // load B for slice-pair sp_ (slices 2*sp_ and 2*sp_+1) into bfr
    #define B_LOAD(sp_)                                                       \
        do {                                                                  \
            _Pragma("unroll")                                                 \
            for (int s2 = 0; s2 < 2; ++s2)                                    \
                _Pragma("unroll")                                             \
                for (int j = 0; j < 2; ++j)                                   \
                    bfr[s2][j] = *reinterpret_cast<const bf16x8*>(            \
                        Wb + (size_t)(n0 + j * 16 + l16) * K_DIM + kc * KC    \
                           + ((sp_) * 2 + s2) * 32 + g * 8);                  \
        } while (0)

    #define COMPUTE_SLICE(s_)                                                 \
        do {                                                                  \
            _Pragma("unroll")                                                 \
            for (int i = 0; i < 8; ++i) {                                     \
                const int row = i * 16 + l16;                                 \
                bf16x8 av = *reinterpret_cast<const bf16x8*>(                 \
                    smem + bufb + row * 256 +                                 \
                    (((s_) * 64 + g * 16) ^ ((row & 7) << 4)));               \
                _Pragma("unroll")                                             \
                for (int j = 0; j < 2; ++j)                                   \
                    acc[i][j] = __builtin_amdgcn_mfma_f32_16x16x32_bf16(      \
                        av, bfr[(s_) & 1][j], acc[i][j], 0, 0, 0);            \
            }                                                                 \
        } while (0)

    // ---- prologue: stage chunk 0 (both col-halves) into buf 0 ----
    STAGE_LOAD(0, 0);
    asm volatile("s_waitcnt vmcnt(0)" ::: "memory");
    STAGE_WRITE(0, 0);
    STAGE_LOAD(0, 1);
    asm volatile("s_waitcnt vmcnt(0)" ::: "memory");
    STAGE_WRITE(0, 1);

    // ---- K loop: 4 chunks of 128, ONE barrier per chunk ----
    #pragma unroll
    for (int kc = 0; kc < NKC; ++kc) {
        BAR();   // buf[kc&1] visible to all; buf[(kc+1)&1] free to write
        const int bufb = (kc & 1) * 32768;

        // phase A: slices 0,1 + stage col-half 0 of next chunk
        B_LOAD(0);                           // oldest -> counted B-use wait
        __builtin_amdgcn_sched_barrier(0);
        if (kc + 1 < NKC) STAGE_LOAD(kc + 1, 0);   // newest; fly over compute
        __builtin_amdgcn_sched_barrier(0);
        COMPUTE_SLICE(0);
        COMPUTE_SLICE(1);
        if (kc + 1 < NKC) {
            asm volatile("s_waitcnt vmcnt(0)" ::: "memory");  // G0 landed (free)
            STAGE_WRITE((kc + 1) & 1, 0);
        }

        // phase B: slices 2,3 + stage col-half 1 (regs reused; the asm
        // "memory" fence above stops these loads hoisting into phase A)
        B_LOAD(1);
        __builtin_amdgcn_sched_barrier(0);
        if (kc + 1 < NKC) STAGE_LOAD(kc + 1, 1);
        __builtin_amdgcn_sched_barrier(0);
        COMPUTE_SLICE(2);
        COMPUTE_SLICE(3);
        if (kc + 1 < NKC) {
            asm volatile("s_waitcnt vmcnt(0)" ::: "memory");
            STAGE_WRITE((kc + 1) & 1, 1);
        }
    }
    #undef STAGE_LOAD
    #undef STAGE_WRITE
    #undef B_LOAD
    #undef COMPUTE_SLICE

    // ---- bias + tanh in regs ----
    // D layout: col = lane&15, row(within 16x16) = (lane>>4)*4 + r
    #pragma unroll
    for (int j = 0; j < 2; ++j) {
        const float bj = bias[n0 + j * 16 + l16];
        #pragma unroll
        for (int i = 0; i < 8; ++i)
            #pragma unroll
            for (int r = 0; r < 4; ++r)
                acc[i][j][r] = fast_tanh(acc[i][j][r] + bj);
    }

    // ---- in-register segmented product, per 64-row half h ----
    // Virtual 64-row group vb = bid*2 + h keeps partial/pass2 layout stable.
    #pragma unroll
    for (int h = 0; h < 2; ++h) {
        const int vb     = bid * 2 + h;
        const int myseg  = seg[m0 + h * 64 + lane];
        const int prevsg = (lane == 0) ? (myseg ^ 1) : seg[m0 + h * 64 + lane - 1];
        uint64_t m = __ballot(myseg != prevsg);              // run-start bits

        while (m) {
            const int start = (int)__builtin_ctzll(m);
            m &= m - 1;
            const int end = m ? (int)__builtin_ctzll(m) : 64;
            const int s   = __shfl(myseg, start);            // run's segment id

            float p[2] = {1.0f, 1.0f};
            #pragma unroll
            for (int i2 = 0; i2 < 4; ++i2)
                #pragma unroll
                for (int r = 0; r < 4; ++r) {
                    const int row = i2 * 16 + g * 4 + r;     // row within half
                    const bool in = (row >= start) && (row < end);
                    #pragma unroll
                    for (int j = 0; j < 2; ++j)
                        p[j] *= in ? acc[h * 4 + i2][j][r] : 1.0f;
                }
            #pragma unroll
            for (int j = 0; j < 2; ++j) {
                p[j] *= __shfl_xor(p[j], 16);
                p[j] *= __shfl_xor(p[j], 32);
            }
            if (g == 0) {
                #pragma unroll
                for (int j = 0; j < 2; ++j) {
                    const int col = n0 + j * 16 + l16;
                    if (start == 0)
                        partial[(size_t)(vb * 2 + 0) * N_RANK + col] = p[j];
                    else if (end == 64)
                        partial[(size_t)(vb * 2 + 1) * N_RANK + col] = p[j];
                    else
                        out[(size_t)s * N_RANK + col] = p[j]; // interior: exclusive
                }
            }
        }
    }
}

// Kernel 3 (pass 2): combine boundary partials over 64-row groups (b = vb).
// Group b owns boundary segment s iff s first appears in group b. Interior
// segments were stored by pass 1; empty segments stay 1.0.
__global__ void pass2_kernel(const int* __restrict__ seg,
                             const float* __restrict__ partial,
                             float* __restrict__ out) {
    const int b   = blockIdx.x;
    const int col = threadIdx.x;      // 0..255
    const int sF    = seg[b * 64];
    const int sL    = seg[b * 64 + 63];
    const int prevL = (b == 0) ? -1 : seg[b * 64 - 1];

    if (prevL < sF) {                 // b owns its first segment
        float p = partial[(size_t)(b * 2 + 0) * N_RANK + col];
        for (int b2 = b + 1; b2 < NB64 && seg[b2 * 64] == sF; ++b2)
            p *= partial[(size_t)(b2 * 2 + 0) * N_RANK + col];
        out[(size_t)sF * N_RANK + col] = p;
    }
    if (sL != sF) {                   // b always owns sL when sL != sF
        float p = partial[(size_t)(b * 2 + 1) * N_RANK + col];
        for (int b2 = b + 1; b2 < NB64 && seg[b2 * 64] == sL; ++b2)
            p *= partial[(size_t)(b2 * 2 + 0) * N_RANK + col];
        out[(size_t)sL * N_RANK + col] = p;
    }
}

extern "C" void kernel_launch(void* const* d_in, const int* in_sizes, int n_in,
                              void* d_out, int out_size, void* d_ws, size_t ws_size,
                              hipStream_t stream) {
    const float* x   = (const float*)d_in[0];
    const float* W   = (const float*)d_in[1];
    const float* b   = (const float*)d_in[2];
    const int*   seg = (const int*)d_in[3];
    float*       out = (float*)d_out;
    __hip_bfloat16* Wb = (__hip_bfloat16*)d_ws;                       // 256 KB
    float* partial = (float*)((char*)d_ws + (1 << 20));               // 4 MB @ +1MB

    prep_kernel<<<(NSEG * N_RANK) / 256, 256, 0, stream>>>(W, Wb, out);
    fused_kernel<<<NBLK, 512, 0, stream>>>(x, Wb, b, seg, out, partial);
    pass2_kernel<<<NB64, 256, 0, stream>>>(seg, partial, out);
}

// Round 19
// 80.744 us; speedup vs baseline: 1.9615x; 1.2092x over previous
//
#include <hip/hip_runtime.h>
#include <hip/hip_bf16.h>
#include <stdint.h>

// Problem constants (from reference)
#define M_TOTAL 131072
#define K_DIM   512
#define N_RANK  256
#define NSEG    1024
#define KC      64              // k-chunk staged in LDS (64 bf16 per row)
#define NKC     (K_DIM / KC)    // 8
#define BM      128             // rows per block
#define NBLK    (M_TOTAL / BM)  // 1024 fused blocks
#define NB64    (M_TOTAL / 64)  // 2048 virtual 64-row groups (pass2 granularity)

typedef __attribute__((ext_vector_type(8))) short bf16x8;
typedef __attribute__((ext_vector_type(4))) float f32x4;

// Raw barrier: lgkmcnt(0) makes my ds_writes visible, vmcnt NOT drained.
#define BAR() do { \
    asm volatile("s_waitcnt lgkmcnt(0)" ::: "memory"); \
    __builtin_amdgcn_s_barrier(); \
} while (0)

__device__ inline short f2b(float f) {
    __hip_bfloat16 h = __float2bfloat16(f);
    return __builtin_bit_cast(short, h);
}

// fast tanh: t = sign(z) * (1 - 2/(e^{2|z|}+1))
__device__ inline float fast_tanh(float z) {
    float e = __expf(2.0f * fabsf(z));
    return copysignf(1.0f - 2.0f / (e + 1.0f), z);
}

// Kernel 1: init out to 1.0 (segment_prod identity for empty segments)
//           + convert W to bf16 in ws
__global__ void prep_kernel(const float* __restrict__ W,
                            __hip_bfloat16* __restrict__ Wb,
                            float* __restrict__ out) {
    int i = blockIdx.x * 256 + threadIdx.x;
    out[i] = 1.0f;
    if (i < N_RANK * K_DIM) Wb[i] = __float2bfloat16(W[i]);
}

// Kernel 2 (pass 1): fused GEMM + bias + tanh + in-register segmented product.
//
// R19 = R12 EXACTLY (best measured: 81.4 us) + s_setprio(1/0) around each
// K-slice's ds_read+MFMA cluster. With 2 resident blocks/CU interleaving
// compute vs staging phases, priority biases the CU scheduler toward the
// compute-phase block (T5 role-diversity). Zero cost, zero register change.
//
// Structure pins (measured): 8-wave col-slice is the ONLY geometry fitting
// the (512,4) 128-reg cap (R13/R14/R17 spilled); KC=64 beats 128 (R18 +16us)
// and BM=128 beats 64 (R15 +20us). bf16 converted ONCE at stage-write
// (R12: -7.4us vs read-time cvt). Single barrier per chunk (R11: -6.7us).
// B-loads oldest in VMEM queue -> counted B-use wait; G-loads newest ->
// fly across compute (R9: -5us).
__launch_bounds__(512, 4)   // reg cap 128; spill canary = WRITE_SIZE balloon
__global__ void fused_kernel(const float* __restrict__ x,
                             const __hip_bfloat16* __restrict__ Wb,
                             const float* __restrict__ bias,
                             const int* __restrict__ seg,
                             float* __restrict__ out,
                             float* __restrict__ partial) {
    const int tid  = threadIdx.x;
    const int wave = tid >> 6;        // 0..7 = column-slice
    const int lane = tid & 63;
    const int l16  = lane & 15;
    const int g    = lane >> 4;       // 0..3 (k-group / row-group)
    const int bid  = blockIdx.x;
    const int m0   = bid * BM;
    const int n0   = wave * 32;

    // LDS: A double-buffer, 2 x (128 rows x 128B bf16) = 32 KB.
    __shared__ alignas(16) char smem[32768];

    // ---- staging geometry: thread covers one 16B f32 slot, 4 slabs ----
    const int srow = tid >> 4;        // 0..31
    const int sc16 = tid & 15;

    f32x4 acc[8][2] = {};             // [m-frag][n-frag]
    f32x4 sg[4];                      // staged f32 for next chunk

    #define STAGE_LOAD(kc_)                                                   \
        do {                                                                  \
            _Pragma("unroll")                                                 \
            for (int it = 0; it < 4; ++it)                                    \
                sg[it] = *reinterpret_cast<const f32x4*>(                     \
                    x + (size_t)(m0 + it * 32 + srow) * K_DIM + (kc_) * KC + sc16 * 4); \
        } while (0)

    #define STAGE_WRITE(buf_)                                                 \
        do {                                                                  \
            _Pragma("unroll")                                                 \
            for (int it = 0; it < 4; ++it) {                                  \
                const int row = it * 32 + srow;                               \
                short4 p;                                                     \
                p.x = f2b(sg[it][0]); p.y = f2b(sg[it][1]);                   \
                p.z = f2b(sg[it][2]); p.w = f2b(sg[it][3]);                   \
                *reinterpret_cast<short4*>(smem + (buf_) * 16384 + row * 128  \
                    + ((sc16 * 8) ^ ((row & 7) << 4))) = p;                   \
            }                                                                 \
        } while (0)

    // ---- prologue: stage chunk 0 into buf 0 ----
    STAGE_LOAD(0);
    asm volatile("s_waitcnt vmcnt(0)" ::: "memory");
    STAGE_WRITE(0);

    // ---- K loop: 8 chunks of 64, ONE barrier per chunk ----
    #pragma unroll
    for (int kc = 0; kc < NKC; ++kc) {
        BAR();   // buf[kc&1] visible to all; buf[(kc+1)&1] free to write

        // 1) B fragments (L2-resident, 4 loads/wave) -- oldest in VMEM queue
        bf16x8 bfr[2][2];
        #pragma unroll
        for (int s = 0; s < 2; ++s)
            #pragma unroll
            for (int j = 0; j < 2; ++j)
                bfr[s][j] = *reinterpret_cast<const bf16x8*>(
                    Wb + (size_t)(n0 + j * 16 + l16) * K_DIM + kc * KC + s * 32 + g * 8);
        __builtin_amdgcn_sched_barrier(0);   // pin: B-loads stay above G-loads

        // 2) issue G loads for chunk kc+1 (newest; fly across compute)
        if (kc + 1 < NKC) STAGE_LOAD(kc + 1);
        __builtin_amdgcn_sched_barrier(0);   // pin: G-loads stay above compute

        // 3) compute chunk kc from LDS buf kc&1 (A-frag = 1 ds_read_b128;
        //    compiler's B-use wait = counted vmcnt, G stays in flight).
        //    setprio(1) biases the CU scheduler toward this wave's MFMA
        //    cluster while the co-resident block issues staging (R19).
        const int bufb = (kc & 1) * 16384;
        __builtin_amdgcn_s_setprio(1);
        #pragma unroll
        for (int s = 0; s < 2; ++s) {
            #pragma unroll
            for (int i = 0; i < 8; ++i) {
                const int row = i * 16 + l16;
                bf16x8 av = *reinterpret_cast<const bf16x8*>(
                    smem + bufb + row * 128 + ((s * 64 + g * 16) ^ ((row & 7) << 4)));
                #pragma unroll
                for (int j = 0; j < 2; ++j)
                    acc[i][j] = __builtin_amdgcn_mfma_f32_16x16x32_bf16(
                        av, bfr[s][j], acc[i][j], 0, 0, 0);
            }
        }
        __builtin_amdgcn_s_setprio(0);

        // 4) convert + write the prefetched chunk (loads had whole compute)
        if (kc + 1 < NKC) {
            asm volatile("s_waitcnt vmcnt(0)" ::: "memory");
            STAGE_WRITE((kc + 1) & 1);
        }
    }
    #undef STAGE_LOAD
    #undef STAGE_WRITE

    // ---- bias + tanh in regs ----
    // D layout: col = lane&15, row(within 16x16) = (lane>>4)*4 + r
    #pragma unroll
    for (int j = 0; j < 2; ++j) {
        const float bj = bias[n0 + j * 16 + l16];
        #pragma unroll
        for (int i = 0; i < 8; ++i)
            #pragma unroll
            for (int r = 0; r < 4; ++r)
                acc[i][j][r] = fast_tanh(acc[i][j][r] + bj);
    }

    // ---- in-register segmented product, per 64-row half h ----
    // Virtual 64-row group vb = bid*2 + h keeps partial/pass2 layout stable.
    #pragma unroll
    for (int h = 0; h < 2; ++h) {
        const int vb     = bid * 2 + h;
        const int myseg  = seg[m0 + h * 64 + lane];
        const int prevsg = (lane == 0) ? (myseg ^ 1) : seg[m0 + h * 64 + lane - 1];
        uint64_t m = __ballot(myseg != prevsg);              // run-start bits

        while (m) {
            const int start = (int)__builtin_ctzll(m);
            m &= m - 1;
            const int end = m ? (int)__builtin_ctzll(m) : 64;
            const int s   = __shfl(myseg, start);            // run's segment id

            float p[2] = {1.0f, 1.0f};
            #pragma unroll
            for (int i2 = 0; i2 < 4; ++i2)
                #pragma unroll
                for (int r = 0; r < 4; ++r) {
                    const int row = i2 * 16 + g * 4 + r;     // row within half
                    const bool in = (row >= start) && (row < end);
                    #pragma unroll
                    for (int j = 0; j < 2; ++j)
                        p[j] *= in ? acc[h * 4 + i2][j][r] : 1.0f;
                }
            #pragma unroll
            for (int j = 0; j < 2; ++j) {
                p[j] *= __shfl_xor(p[j], 16);
                p[j] *= __shfl_xor(p[j], 32);
            }
            if (g == 0) {
                #pragma unroll
                for (int j = 0; j < 2; ++j) {
                    const int col = n0 + j * 16 + l16;
                    if (start == 0)
                        partial[(size_t)(vb * 2 + 0) * N_RANK + col] = p[j];
                    else if (end == 64)
                        partial[(size_t)(vb * 2 + 1) * N_RANK + col] = p[j];
                    else
                        out[(size_t)s * N_RANK + col] = p[j]; // interior: exclusive
                }
            }
        }
    }
}

// Kernel 3 (pass 2): combine boundary partials over 64-row groups (b = vb).
// Group b owns boundary segment s iff s first appears in group b. Interior
// segments were stored by pass 1; empty segments stay 1.0.
__global__ void pass2_kernel(const int* __restrict__ seg,
                             const float* __restrict__ partial,
                             float* __restrict__ out) {
    const int b   = blockIdx.x;
    const int col = threadIdx.x;      // 0..255
    const int sF    = seg[b * 64];
    const int sL    = seg[b * 64 + 63];
    const int prevL = (b == 0) ? -1 : seg[b * 64 - 1];

    if (prevL < sF) {                 // b owns its first segment
        float p = partial[(size_t)(b * 2 + 0) * N_RANK + col];
        for (int b2 = b + 1; b2 < NB64 && seg[b2 * 64] == sF; ++b2)
            p *= partial[(size_t)(b2 * 2 + 0) * N_RANK + col];
        out[(size_t)sF * N_RANK + col] = p;
    }
    if (sL != sF) {                   // b always owns sL when sL != sF
        float p = partial[(size_t)(b * 2 + 1) * N_RANK + col];
        for (int b2 = b + 1; b2 < NB64 && seg[b2 * 64] == sL; ++b2)
            p *= partial[(size_t)(b2 * 2 + 0) * N_RANK + col];
        out[(size_t)sL * N_RANK + col] = p;
    }
}

extern "C" void kernel_launch(void* const* d_in, const int* in_sizes, int n_in,
                              void* d_out, int out_size, void* d_ws, size_t ws_size,
                              hipStream_t stream) {
    const float* x   = (const float*)d_in[0];
    const float* W   = (const float*)d_in[1];
    const float* b   = (const float*)d_in[2];
    const int*   seg = (const int*)d_in[3];
    float*       out = (float*)d_out;
    __hip_bfloat16* Wb = (__hip_bfloat16*)d_ws;                       // 256 KB
    float* partial = (float*)((char*)d_ws + (1 << 20));               // 4 MB @ +1MB

    prep_kernel<<<(NSEG * N_RANK) / 256, 256, 0, stream>>>(W, Wb, out);
    fused_kernel<<<NBLK, 512, 0, stream>>>(x, Wb, b, seg, out, partial);
    pass2_kernel<<<NB64, 256, 0, stream>>>(seg, partial, out);
}